// Round 3
// baseline (715.598 us; speedup 1.0000x reference)
//
#include <hip/hip_runtime.h>
#include <math.h>

// R3: single fused kernel, plain launch + software grid barrier (cooperative
// launch failed to capture in R2). Wave-level GEMM units for balanced single
// rounds; latency-bound partial-reduces widened (8 chains in flight).

// Problem constants
#define B64 64
#define IN_SH 10000
#define EXP_SH 53
#define HID 1500
#define NPAD1 1536
#define NBC 2048
#define K2 1553
#define GRID 512            // 2 blocks/CU guaranteed co-resident
#define KS1 20              // gemm1 split-K chunks; 96 coltiles * 20 = 1920 wave-units
#define KST1 16             // 16 steps of 32 -> kchunk 512 (20*512 = 10240)
#define KS2 13              // 13*128 = 1664 >= 1553; 128 coltiles * 13 = 1664 wave-units
#define KST2 4              // kchunk 128
#define XSTEP 52            // Xf k-steps (1664/32), zero-padded past 1553
#define CMCH 32
#define WLDS 640            // dwords per wave LDS buffer (32 rows * 20)
#define ACC1 (NPAD1 * 64)   // floats per gemm1 partial
#define ACC2 (NBC * 64)     // floats per gemm2 partial

using short8  = __attribute__((ext_vector_type(8))) short;
using floatx4 = __attribute__((ext_vector_type(4))) float;
using uintx4  = __attribute__((ext_vector_type(4))) unsigned int;

__device__ __forceinline__ unsigned short f2bf(float f) {
    unsigned u = __float_as_uint(f);
    u += 0x7fffu + ((u >> 16) & 1u);   // RNE
    return (unsigned short)(u >> 16);
}

// Software grid barrier: release-fence + counter inc; spin (bounded, so a
// co-residency failure fails the bench instead of hanging); acquire-fence.
__device__ __forceinline__ void gbar(unsigned* bar, unsigned target) {
    __threadfence();                 // publish my writes (L2 writeback, device scope)
    __syncthreads();
    if (threadIdx.x == 0) {
        __hip_atomic_fetch_add(bar, 1u, __ATOMIC_ACQ_REL, __HIP_MEMORY_SCOPE_AGENT);
        int guard = 1 << 21;
        while (__hip_atomic_load(bar, __ATOMIC_ACQUIRE, __HIP_MEMORY_SCOPE_AGENT) < target
               && --guard) {
            __builtin_amdgcn_s_sleep(2);
        }
    }
    __syncthreads();
    __threadfence();                 // invalidate stale caches before reading remote data
}

__device__ __forceinline__ void load_b4(const unsigned short* __restrict__ bf,
                                        int stg, uintx4 bv[4]) {
    #pragma unroll
    for (int s = 0; s < 4; s++)
        bv[s] = *(const uintx4*)(bf + (size_t)(stg * 4 + s) * 512);
}

// Wave-scoped barrier-free MFMA GEMM unit: one 16-column tile x one K-chunk.
// Wave-private LDS double buffer; plain stores into per-chunk partials.
template<int KSTEPS>
__device__ __forceinline__ void gemm_wave(
    const float* __restrict__ W, const unsigned short* __restrict__ Bfc,
    float* __restrict__ pbuf, int N, int K, int ldw, int n0, int k0,
    int lane, float* __restrict__ ldsw)
{
    int q    = lane >> 4;
    int l15  = lane & 15;
    bool fast = (n0 + 16 <= N) && (k0 + KSTEPS * 32 <= K);
    int kl  = lane >> 2;                    // 0..15 (staging row)
    int c4  = (lane & 3) * 4;               // staging col offset

    const unsigned short* bf = Bfc + (size_t)lane * 8;

    floatx4 acc[4];
    #pragma unroll
    for (int s = 0; s < 4; s++) acc[s] = (floatx4){0.f, 0.f, 0.f, 0.f};

    floatx4 g[2][2];

    #define GLB(st, slot)                                                        \
        {                                                                        \
            int kb_ = k0 + (st) * 32;                                            \
            _Pragma("unroll")                                                    \
            for (int i_ = 0; i_ < 2; i_++) {                                     \
                int kg_ = kb_ + kl + 16 * i_;                                    \
                if (fast) {                                                      \
                    g[slot][i_] = *(const floatx4*)(W + (size_t)kg_ * ldw + n0 + c4); \
                } else {                                                         \
                    _Pragma("unroll")                                            \
                    for (int j_ = 0; j_ < 4; j_++)                               \
                        g[slot][i_][j_] = (kg_ < K && n0 + c4 + j_ < N)          \
                            ? W[(size_t)kg_ * ldw + n0 + c4 + j_] : 0.f;         \
                }                                                                \
            }                                                                    \
        }
    #define LWR(buf, slot)                                                       \
        {                                                                        \
            _Pragma("unroll")                                                    \
            for (int i_ = 0; i_ < 2; i_++)                                       \
                *(floatx4*)(ldsw + (buf) * WLDS + (kl + 16 * i_) * 20 + c4) = g[slot][i_]; \
        }

    GLB(0, 0);
    if (KSTEPS > 1) GLB(1, 1);
    LWR(0, 0);

    uintx4 bv[2][4];
    load_b4(bf, 0, bv[0]);
    if (KSTEPS > 1) load_b4(bf, 1, bv[1]);

    #pragma unroll
    for (int st = 0; st < KSTEPS; st++) {
        const int s = st & 1;
        const float* lb = ldsw + s * WLDS;

        short8 af;
        #pragma unroll
        for (int j = 0; j < 8; j++)
            af[j] = (short)f2bf(lb[(q * 8 + j) * 20 + l15]);

        uintx4 bt[4];
        if (st + 2 < KSTEPS) {
            GLB(st + 2, s);
            load_b4(bf, st + 2, bt);
        }

        #pragma unroll
        for (int m = 0; m < 4; m++) {
            short8 bf8 = __builtin_bit_cast(short8, bv[s][m]);
            acc[m] = __builtin_amdgcn_mfma_f32_16x16x32_bf16(af, bf8, acc[m], 0, 0, 0);
        }

        if (st + 1 < KSTEPS) LWR(1 - s, 1 - s);
        if (st + 2 < KSTEPS) {
            #pragma unroll
            for (int m = 0; m < 4; m++) bv[s][m] = bt[m];
        }
    }
    #undef GLB
    #undef LWR

    int nrow = n0 + q * 4;
    #pragma unroll
    for (int s = 0; s < 4; s++) {
        #pragma unroll
        for (int rr = 0; rr < 4; rr++)
            pbuf[(size_t)(nrow + rr) * 64 + s * 16 + l15] = acc[s][rr];
    }
}

__global__ __launch_bounds__(256, 2) void fused_k(
    const float* __restrict__ gos, const float* __restrict__ expx,
    const float* __restrict__ W1, const float* __restrict__ b1,
    const float* __restrict__ W2, const float* __restrict__ b2,
    const float* __restrict__ hpo, float* __restrict__ out,
    unsigned short* __restrict__ gosBf, unsigned short* __restrict__ Xf,
    float* __restrict__ cm, float* __restrict__ cmr,
    float* __restrict__ hpre_p, float* __restrict__ logits_p,
    unsigned* __restrict__ bar)
{
    __shared__ float lds[4 * 2 * WLDS];
    const int bi   = blockIdx.x;
    const int tid  = threadIdx.x;
    const int lane = tid & 63;
    const int wid  = tid >> 6;

    // ---- P0: build gosBf (320 units) | hpo colmax (256 units); grid-stride ----
    for (int u = bi; u < 576; u += GRID) {
        if (u < 320) {
            int t    = u * 256 + tid;            // [0, 81920)
            int sgrp = (t >> 6) & 3;
            int step = t >> 8;                   // [0, 320)
            int q    = lane >> 4;
            int l15  = lane & 15;
            int b    = sgrp * 16 + l15;
            int k0   = step * 32 + q * 8;
            const float* p = gos + (size_t)b * IN_SH + k0;
            unsigned int o[4];
            #pragma unroll
            for (int i = 0; i < 4; i++) {
                float lo = (k0 + 2 * i     < IN_SH) ? p[2 * i]     : 0.f;
                float hi = (k0 + 2 * i + 1 < IN_SH) ? p[2 * i + 1] : 0.f;
                o[i] = (unsigned)f2bf(lo) | ((unsigned)f2bf(hi) << 16);
            }
            uintx4 v; v.x = o[0]; v.y = o[1]; v.z = o[2]; v.w = o[3];
            *(uintx4*)(gosBf + (size_t)t * 8) = v;
        } else {
            int uu = u - 320;                    // [0, 256)
            int j  = (uu & 7) * 256 + tid;       // 0..2047
            int i0 = (uu >> 3) * 64;
            float m = 0.0f;
            #pragma unroll 16
            for (int i = i0; i < i0 + 64; i++)
                m = fmaxf(m, hpo[(size_t)i * NBC + j]);
            cm[(uu >> 3) * NBC + j] = m;
        }
    }
    gbar(bar, GRID);

    // ---- P1: GEMM1, 96 coltiles x 20 chunks = 1920 wave-units (1 round) ----
    {
        int wu = bi * 4 + wid;                   // [0, 2048)
        if (wu < 96 * KS1) {
            int c16 = wu % 96;
            int by  = wu / 96;
            gemm_wave<KST1>(W1, gosBf + (size_t)by * (KST1 * 4) * 512,
                            hpre_p + (size_t)by * ACC1, HID, IN_SH, HID,
                            c16 * 16, by * (KST1 * 32), lane,
                            lds + wid * (2 * WLDS));
        }
    }
    gbar(bar, 2 * GRID);

    // ---- P2: reduce 20 partials + bias + GELU + concat -> Xf (208 units,
    //          8 load-chains/thread) | reduce cm -> cmr (8 units) ----
    if (bi < 4 * XSTEP) {
        int step = bi >> 2, jp = bi & 3;
        int sgrp = tid >> 6;
        int q    = lane >> 4;
        int l15  = lane & 15;
        int b    = sgrp * 16 + l15;
        int n0   = step * 32 + q * 8 + jp * 2;
        float sv0, sv1;
        if (n0 + 1 < HID) {
            float a0 = 0.f, a1 = 0.f, a2 = 0.f, a3 = 0.f;
            float c0 = 0.f, c1 = 0.f, c2 = 0.f, c3 = 0.f;
            const float* p = hpre_p + (size_t)n0 * 64 + b;
            #pragma unroll
            for (int ks = 0; ks < KS1; ks += 4) {
                a0 += p[0];                      c0 += p[64];
                a1 += p[ACC1];                   c1 += p[ACC1 + 64];
                a2 += p[2 * (size_t)ACC1];       c2 += p[2 * (size_t)ACC1 + 64];
                a3 += p[3 * (size_t)ACC1];       c3 += p[3 * (size_t)ACC1 + 64];
                p  += (size_t)4 * ACC1;
            }
            sv0 = b1[n0]     + ((a0 + a1) + (a2 + a3));
            sv1 = b1[n0 + 1] + ((c0 + c1) + (c2 + c3));
            sv0 = 0.5f * sv0 * (1.0f + erff(sv0 * 0.70710678118654752f));
            sv1 = 0.5f * sv1 * (1.0f + erff(sv1 * 0.70710678118654752f));
        } else {
            float vv[2];
            #pragma unroll
            for (int jj = 0; jj < 2; jj++) {
                int n = n0 + jj;
                float v = 0.f;
                if (n < HID) {
                    float s = b1[n];
                    for (int ks = 0; ks < KS1; ks++)
                        s += hpre_p[(size_t)ks * ACC1 + (size_t)n * 64 + b];
                    v = 0.5f * s * (1.0f + erff(s * 0.70710678118654752f));
                } else if (n < HID + EXP_SH) {
                    v = expx[b * EXP_SH + (n - HID)];
                }
                vv[jj] = v;
            }
            sv0 = vv[0]; sv1 = vv[1];
        }
        unsigned o = (unsigned)f2bf(sv0) | ((unsigned)f2bf(sv1) << 16);
        size_t tq = (size_t)step * 256 + sgrp * 64 + q * 16 + l15;
        *(unsigned*)(Xf + tq * 8 + jp * 2) = o;
    } else if (bi < 4 * XSTEP + 8) {
        int j = (bi - 4 * XSTEP) * 256 + tid;    // 0..2047
        float m = 0.f;
        #pragma unroll
        for (int c = 0; c < CMCH; c++) m = fmaxf(m, cm[c * NBC + j]);
        cmr[j] = m;
    }
    gbar(bar, 3 * GRID);

    // ---- P3: GEMM2, 128 coltiles x 13 chunks = 1664 wave-units (1 round) ----
    {
        int wu = bi * 4 + wid;
        if (wu < 128 * KS2) {
            int c16 = wu & 127;
            int by  = wu >> 7;
            gemm_wave<KST2>(W2, Xf + (size_t)by * (KST2 * 4) * 512,
                            logits_p + (size_t)by * ACC2, NBC, K2, NBC,
                            c16 * 16, by * (KST2 * 32), lane,
                            lds + wid * (2 * WLDS));
        }
    }
    gbar(bar, 4 * GRID);

    // ---- P4: reduce 13 partials + bias + sigmoid + *cmr -> out (256 units) ----
    if (bi < 256) {
        int j0 = bi * 8;
        #pragma unroll
        for (int e = 0; e < 2; e++) {
            int lin = e * 256 + tid;             // j-major, b-minor
            int jj  = lin >> 6;                  // 0..7
            int b   = lin & 63;
            int j   = j0 + jj;
            float s = b2[j];
            const float* p = logits_p + (size_t)j * 64 + b;
            #pragma unroll
            for (int ks = 0; ks < KS2; ks++)
                s += p[(size_t)ks * ACC2];
            float sig = 1.0f / (1.0f + expf(-s));
            lds[jj * 65 + b] = sig * cmr[j];
        }
        __syncthreads();
        #pragma unroll
        for (int e = 0; e < 2; e++) {
            int lin = e * 256 + tid;             // b-major, j-minor
            int b   = lin >> 3;                  // 0..63
            int jj  = lin & 7;
            out[(size_t)b * NBC + j0 + jj] = lds[jj * 65 + b];
        }
    }
}

extern "C" void kernel_launch(void* const* d_in, const int* in_sizes, int n_in,
                              void* d_out, int out_size, void* d_ws, size_t ws_size,
                              hipStream_t stream) {
    const float* gos  = (const float*)d_in[0];
    const float* expx = (const float*)d_in[1];
    const float* W1   = (const float*)d_in[2];
    const float* b1   = (const float*)d_in[3];
    const float* W2   = (const float*)d_in[4];
    const float* b2   = (const float*)d_in[5];
    const float* hpo  = (const float*)d_in[6];
    float* out = (float*)d_out;

    // workspace layout (16B-aligned offsets)
    char* ws = (char*)d_ws;
    unsigned short* gosBf = (unsigned short*)ws;                   // 1,310,720
    unsigned short* Xf    = (unsigned short*)(ws + 1310720);       //   212,992
    float* cm       = (float*)(ws + 1523712);                      //   262,144
    float* cmr      = (float*)(ws + 1785856);                      //     8,192
    unsigned* bar   = (unsigned*)(ws + 1794048);                   //        64
    float* hpre_p   = (float*)(ws + 1794112);                      // 20*393,216 = 7,864,320
    float* logits_p = (float*)(ws + 9658432);                      // 13*524,288 = 6,815,744
    // total ~16.5 MB

    hipMemsetAsync(bar, 0, 64, stream);   // barrier counter (graph-capture-safe)

    fused_k<<<GRID, 256, 0, stream>>>(gos, expx, W1, b1, W2, b2, hpo, out,
                                      gosBf, Xf, cm, cmr, hpre_p, logits_p, bar);
}

// Round 6
// 317.353 us; speedup vs baseline: 2.2549x; 2.2549x over previous
//
#include <hip/hip_runtime.h>
#include <math.h>

// R6: barrier poll fixed for cross-XCD coherence WITHOUT cache maintenance.
// R3: ACQUIRE polls -> buffer_inv per poll -> L2 destroyed -> 630us.
// R5: RELAXED polls -> may read own-XCD stale L2 copy forever -> livelock
//     (suspected container kill). Now: inline-asm global_load sc0 sc1 reads
//     the device coherent point directly (no invalidate, no staleness, no
//     RMW serialization); single ACQUIRE load (one buffer_inv) on exit.

// Problem constants
#define B64 64
#define IN_SH 10000
#define EXP_SH 53
#define HID 1500
#define NPAD1 1536
#define NBC 2048
#define K2 1553
#define GRID 512            // 2 blocks/CU guaranteed co-resident
#define KS1 20              // gemm1 split-K chunks; 96 coltiles * 20 = 1920 wave-units
#define KST1 16             // 16 steps of 32 -> kchunk 512 (20*512 = 10240)
#define KS2 13              // 13*128 = 1664 >= 1553; 128 coltiles * 13 = 1664 wave-units
#define KST2 4              // kchunk 128
#define XSTEP 52            // Xf k-steps (1664/32), zero-padded past 1553
#define CMCH 32
#define WLDS 640            // dwords per wave LDS buffer (32 rows * 20)
#define ACC1 (NPAD1 * 64)   // floats per gemm1 partial
#define ACC2 (NBC * 64)     // floats per gemm2 partial

using short8  = __attribute__((ext_vector_type(8))) short;
using floatx4 = __attribute__((ext_vector_type(4))) float;
using uintx4  = __attribute__((ext_vector_type(4))) unsigned int;

__device__ __forceinline__ unsigned short f2bf(float f) {
    unsigned u = __float_as_uint(f);
    u += 0x7fffu + ((u >> 16) & 1u);   // RNE
    return (unsigned short)(u >> 16);
}

// Device-coherent read of the barrier counter: sc0+sc1 bypasses L1 and the
// per-XCD L2, reading the coherent point. No cache invalidation side effect.
__device__ __forceinline__ unsigned coh_read(const unsigned* p) {
    unsigned v;
    asm volatile("global_load_dword %0, %1, off sc0 sc1\n\t"
                 "s_waitcnt vmcnt(0)"
                 : "=v"(v) : "v"(p) : "memory");
    return v;
}

// Software grid barrier. Arrive: RELEASE fetch_add (writes back this XCD's
// dirty L2 once -- publishes partials device-wide). Wait: coherent-point
// polls (no invalidation, no staleness). Exit: one ACQUIRE load per block
// (single buffer_inv for the CU/XCD) before releasing the block's waves.
__device__ __forceinline__ void gbar(unsigned* bar, unsigned target) {
    __syncthreads();
    if (threadIdx.x == 0) {
        __hip_atomic_fetch_add(bar, 1u, __ATOMIC_RELEASE, __HIP_MEMORY_SCOPE_AGENT);
        int guard = 1 << 15;            // bounded: fail loud (~15ms), never hang
        while (coh_read(bar) < target && --guard) {
            __builtin_amdgcn_s_sleep(8);
        }
        (void)__hip_atomic_load(bar, __ATOMIC_ACQUIRE, __HIP_MEMORY_SCOPE_AGENT);
    }
    __syncthreads();
}

__device__ __forceinline__ void load_b4(const unsigned short* __restrict__ bf,
                                        int stg, uintx4 bv[4]) {
    #pragma unroll
    for (int s = 0; s < 4; s++)
        bv[s] = *(const uintx4*)(bf + (size_t)(stg * 4 + s) * 512);
}

// Wave-scoped barrier-free MFMA GEMM unit: one 16-column tile x one K-chunk.
// Wave-private LDS double buffer; plain stores into per-chunk partials.
template<int KSTEPS>
__device__ __forceinline__ void gemm_wave(
    const float* __restrict__ W, const unsigned short* __restrict__ Bfc,
    float* __restrict__ pbuf, int N, int K, int ldw, int n0, int k0,
    int lane, float* __restrict__ ldsw)
{
    int q    = lane >> 4;
    int l15  = lane & 15;
    bool fast = (n0 + 16 <= N) && (k0 + KSTEPS * 32 <= K);
    int kl  = lane >> 2;                    // 0..15 (staging row)
    int c4  = (lane & 3) * 4;               // staging col offset

    const unsigned short* bf = Bfc + (size_t)lane * 8;

    floatx4 acc[4];
    #pragma unroll
    for (int s = 0; s < 4; s++) acc[s] = (floatx4){0.f, 0.f, 0.f, 0.f};

    floatx4 g[2][2];

    #define GLB(st, slot)                                                        \
        {                                                                        \
            int kb_ = k0 + (st) * 32;                                            \
            _Pragma("unroll")                                                    \
            for (int i_ = 0; i_ < 2; i_++) {                                     \
                int kg_ = kb_ + kl + 16 * i_;                                    \
                if (fast) {                                                      \
                    g[slot][i_] = *(const floatx4*)(W + (size_t)kg_ * ldw + n0 + c4); \
                } else {                                                         \
                    _Pragma("unroll")                                            \
                    for (int j_ = 0; j_ < 4; j_++)                               \
                        g[slot][i_][j_] = (kg_ < K && n0 + c4 + j_ < N)          \
                            ? W[(size_t)kg_ * ldw + n0 + c4 + j_] : 0.f;         \
                }                                                                \
            }                                                                    \
        }
    #define LWR(buf, slot)                                                       \
        {                                                                        \
            _Pragma("unroll")                                                    \
            for (int i_ = 0; i_ < 2; i_++)                                       \
                *(floatx4*)(ldsw + (buf) * WLDS + (kl + 16 * i_) * 20 + c4) = g[slot][i_]; \
        }

    GLB(0, 0);
    if (KSTEPS > 1) GLB(1, 1);
    LWR(0, 0);

    uintx4 bv[2][4];
    load_b4(bf, 0, bv[0]);
    if (KSTEPS > 1) load_b4(bf, 1, bv[1]);

    #pragma unroll
    for (int st = 0; st < KSTEPS; st++) {
        const int s = st & 1;
        const float* lb = ldsw + s * WLDS;

        short8 af;
        #pragma unroll
        for (int j = 0; j < 8; j++)
            af[j] = (short)f2bf(lb[(q * 8 + j) * 20 + l15]);

        uintx4 bt[4];
        if (st + 2 < KSTEPS) {
            GLB(st + 2, s);
            load_b4(bf, st + 2, bt);
        }

        #pragma unroll
        for (int m = 0; m < 4; m++) {
            short8 bf8 = __builtin_bit_cast(short8, bv[s][m]);
            acc[m] = __builtin_amdgcn_mfma_f32_16x16x32_bf16(af, bf8, acc[m], 0, 0, 0);
        }

        if (st + 1 < KSTEPS) LWR(1 - s, 1 - s);
        if (st + 2 < KSTEPS) {
            #pragma unroll
            for (int m = 0; m < 4; m++) bv[s][m] = bt[m];
        }
    }
    #undef GLB
    #undef LWR

    int nrow = n0 + q * 4;
    #pragma unroll
    for (int s = 0; s < 4; s++) {
        #pragma unroll
        for (int rr = 0; rr < 4; rr++)
            pbuf[(size_t)(nrow + rr) * 64 + s * 16 + l15] = acc[s][rr];
    }
}

__global__ __launch_bounds__(256, 2) void fused_k(
    const float* __restrict__ gos, const float* __restrict__ expx,
    const float* __restrict__ W1, const float* __restrict__ b1,
    const float* __restrict__ W2, const float* __restrict__ b2,
    const float* __restrict__ hpo, float* __restrict__ out,
    unsigned short* __restrict__ gosBf, unsigned short* __restrict__ Xf,
    float* __restrict__ cm, float* __restrict__ cmr,
    float* __restrict__ hpre_p, float* __restrict__ logits_p,
    unsigned* __restrict__ bar)
{
    __shared__ float lds[4 * 2 * WLDS];
    const int bi   = blockIdx.x;
    const int tid  = threadIdx.x;
    const int lane = tid & 63;
    const int wid  = tid >> 6;

    // ---- P0: build gosBf (320 units) | hpo colmax (256 units); grid-stride ----
    for (int u = bi; u < 576; u += GRID) {
        if (u < 320) {
            int t    = u * 256 + tid;            // [0, 81920)
            int sgrp = (t >> 6) & 3;
            int step = t >> 8;                   // [0, 320)
            int q    = lane >> 4;
            int l15  = lane & 15;
            int b    = sgrp * 16 + l15;
            int k0   = step * 32 + q * 8;
            const float* p = gos + (size_t)b * IN_SH + k0;
            unsigned int o[4];
            #pragma unroll
            for (int i = 0; i < 4; i++) {
                float lo = (k0 + 2 * i     < IN_SH) ? p[2 * i]     : 0.f;
                float hi = (k0 + 2 * i + 1 < IN_SH) ? p[2 * i + 1] : 0.f;
                o[i] = (unsigned)f2bf(lo) | ((unsigned)f2bf(hi) << 16);
            }
            uintx4 v; v.x = o[0]; v.y = o[1]; v.z = o[2]; v.w = o[3];
            *(uintx4*)(gosBf + (size_t)t * 8) = v;
        } else {
            int uu = u - 320;                    // [0, 256)
            int j  = (uu & 7) * 256 + tid;       // 0..2047
            int i0 = (uu >> 3) * 64;
            float m = 0.0f;
            #pragma unroll 16
            for (int i = i0; i < i0 + 64; i++)
                m = fmaxf(m, hpo[(size_t)i * NBC + j]);
            cm[(uu >> 3) * NBC + j] = m;
        }
    }
    gbar(bar, GRID);

    // ---- P1: GEMM1, 96 coltiles x 20 chunks = 1920 wave-units (1 round) ----
    {
        int wu = bi * 4 + wid;                   // [0, 2048)
        if (wu < 96 * KS1) {
            int c16 = wu % 96;
            int by  = wu / 96;
            gemm_wave<KST1>(W1, gosBf + (size_t)by * (KST1 * 4) * 512,
                            hpre_p + (size_t)by * ACC1, HID, IN_SH, HID,
                            c16 * 16, by * (KST1 * 32), lane,
                            lds + wid * (2 * WLDS));
        }
    }
    gbar(bar, 2 * GRID);

    // ---- P2: reduce 20 partials + bias + GELU + concat -> Xf (208 units,
    //          8 load-chains/thread) | reduce cm -> cmr (8 units) ----
    if (bi < 4 * XSTEP) {
        int step = bi >> 2, jp = bi & 3;
        int sgrp = tid >> 6;
        int q    = lane >> 4;
        int l15  = lane & 15;
        int b    = sgrp * 16 + l15;
        int n0   = step * 32 + q * 8 + jp * 2;
        float sv0, sv1;
        if (n0 + 1 < HID) {
            float a0 = 0.f, a1 = 0.f, a2 = 0.f, a3 = 0.f;
            float c0 = 0.f, c1 = 0.f, c2 = 0.f, c3 = 0.f;
            const float* p = hpre_p + (size_t)n0 * 64 + b;
            #pragma unroll
            for (int ks = 0; ks < KS1; ks += 4) {
                a0 += p[0];                      c0 += p[64];
                a1 += p[ACC1];                   c1 += p[ACC1 + 64];
                a2 += p[2 * (size_t)ACC1];       c2 += p[2 * (size_t)ACC1 + 64];
                a3 += p[3 * (size_t)ACC1];       c3 += p[3 * (size_t)ACC1 + 64];
                p  += (size_t)4 * ACC1;
            }
            sv0 = b1[n0]     + ((a0 + a1) + (a2 + a3));
            sv1 = b1[n0 + 1] + ((c0 + c1) + (c2 + c3));
            sv0 = 0.5f * sv0 * (1.0f + erff(sv0 * 0.70710678118654752f));
            sv1 = 0.5f * sv1 * (1.0f + erff(sv1 * 0.70710678118654752f));
        } else {
            float vv[2];
            #pragma unroll
            for (int jj = 0; jj < 2; jj++) {
                int n = n0 + jj;
                float v = 0.f;
                if (n < HID) {
                    float s = b1[n];
                    for (int ks = 0; ks < KS1; ks++)
                        s += hpre_p[(size_t)ks * ACC1 + (size_t)n * 64 + b];
                    v = 0.5f * s * (1.0f + erff(s * 0.70710678118654752f));
                } else if (n < HID + EXP_SH) {
                    v = expx[b * EXP_SH + (n - HID)];
                }
                vv[jj] = v;
            }
            sv0 = vv[0]; sv1 = vv[1];
        }
        unsigned o = (unsigned)f2bf(sv0) | ((unsigned)f2bf(sv1) << 16);
        size_t tq = (size_t)step * 256 + sgrp * 64 + q * 16 + l15;
        *(unsigned*)(Xf + tq * 8 + jp * 2) = o;
    } else if (bi < 4 * XSTEP + 8) {
        int j = (bi - 4 * XSTEP) * 256 + tid;    // 0..2047
        float m = 0.f;
        #pragma unroll
        for (int c = 0; c < CMCH; c++) m = fmaxf(m, cm[c * NBC + j]);
        cmr[j] = m;
    }
    gbar(bar, 3 * GRID);

    // ---- P3: GEMM2, 128 coltiles x 13 chunks = 1664 wave-units (1 round) ----
    {
        int wu = bi * 4 + wid;
        if (wu < 128 * KS2) {
            int c16 = wu & 127;
            int by  = wu >> 7;
            gemm_wave<KST2>(W2, Xf + (size_t)by * (KST2 * 4) * 512,
                            logits_p + (size_t)by * ACC2, NBC, K2, NBC,
                            c16 * 16, by * (KST2 * 32), lane,
                            lds + wid * (2 * WLDS));
        }
    }
    gbar(bar, 4 * GRID);

    // ---- P4: reduce 13 partials + bias + sigmoid + *cmr -> out (256 units) ----
    if (bi < 256) {
        int j0 = bi * 8;
        #pragma unroll
        for (int e = 0; e < 2; e++) {
            int lin = e * 256 + tid;             // j-major, b-minor
            int jj  = lin >> 6;                  // 0..7
            int b   = lin & 63;
            int j   = j0 + jj;
            float s = b2[j];
            const float* p = logits_p + (size_t)j * 64 + b;
            #pragma unroll
            for (int ks = 0; ks < KS2; ks++)
                s += p[(size_t)ks * ACC2];
            float sig = 1.0f / (1.0f + expf(-s));
            lds[jj * 65 + b] = sig * cmr[j];
        }
        __syncthreads();
        #pragma unroll
        for (int e = 0; e < 2; e++) {
            int lin = e * 256 + tid;             // b-major, j-minor
            int b   = lin >> 3;                  // 0..63
            int jj  = lin & 7;
            out[(size_t)b * NBC + j0 + jj] = lds[jj * 65 + b];
        }
    }
}

extern "C" void kernel_launch(void* const* d_in, const int* in_sizes, int n_in,
                              void* d_out, int out_size, void* d_ws, size_t ws_size,
                              hipStream_t stream) {
    const float* gos  = (const float*)d_in[0];
    const float* expx = (const float*)d_in[1];
    const float* W1   = (const float*)d_in[2];
    const float* b1   = (const float*)d_in[3];
    const float* W2   = (const float*)d_in[4];
    const float* b2   = (const float*)d_in[5];
    const float* hpo  = (const float*)d_in[6];
    float* out = (float*)d_out;

    // workspace layout (16B-aligned offsets)
    char* ws = (char*)d_ws;
    unsigned short* gosBf = (unsigned short*)ws;                   // 1,310,720
    unsigned short* Xf    = (unsigned short*)(ws + 1310720);       //   212,992
    float* cm       = (float*)(ws + 1523712);                      //   262,144
    float* cmr      = (float*)(ws + 1785856);                      //     8,192
    unsigned* bar   = (unsigned*)(ws + 1794048);                   //        64
    float* hpre_p   = (float*)(ws + 1794112);                      // 20*393,216 = 7,864,320
    float* logits_p = (float*)(ws + 9658432);                      // 13*524,288 = 6,815,744
    // total ~16.5 MB

    (void)hipMemsetAsync(bar, 0, 64, stream);   // barrier counter (graph-capture-safe)

    fused_k<<<GRID, 256, 0, stream>>>(gos, expx, W1, b1, W2, b2, hpo, out,
                                      gosBf, Xf, cm, cmr, hpre_p, logits_p, bar);
}

// Round 7
// 153.654 us; speedup vs baseline: 4.6572x; 2.0654x over previous
//
#include <hip/hip_runtime.h>
#include <math.h>

// R7: back to 5-kernel chain (no grid barrier). GEMM core rebuilt around
// global_load_lds + 4-slot LDS ring + counted vmcnt (fixes the ~75B/wave
// in-flight starvation diagnosed via Little's law from R6's 412 GB/s).
// Combine/final rewritten as coalesced flat reduces.

// Problem constants
#define B64 64
#define IN_SH 10000
#define EXP_SH 53
#define HID 1500
#define NPAD1 1536
#define NBC 2048
#define K2 1553
#define KS1 20              // gemm1 K-chunks: 24 coltiles x 20 = 480 gemm blocks
#define KST1 16             // 16 steps of 32 -> kchunk 512 (20*512=10240)
#define KS2 13              // 13*128 = 1664 >= 1553
#define KST2 4              // kchunk 128
#define NSTEP 52            // Xf k-steps (1664/32)
#define CMCH 32
#define ACC1 (NPAD1 * 64)   // floats per gemm1 partial
#define ACC2 (NBC * 64)     // floats per gemm2 partial

using short8  = __attribute__((ext_vector_type(8))) short;
using floatx4 = __attribute__((ext_vector_type(4))) float;
using uintx4  = __attribute__((ext_vector_type(4))) unsigned int;

__device__ __forceinline__ unsigned short f2bf(float f) {
    unsigned u = __float_as_uint(f);
    u += 0x7fffu + ((u >> 16) & 1u);   // RNE
    return (unsigned short)(u >> 16);
}

// ---- async global->LDS staging (16B/lane; LDS dest = uniform base + lane*16)
typedef __attribute__((address_space(3))) void lds_v;
typedef __attribute__((address_space(1))) const void glb_v;
__device__ __forceinline__ void gll16(const float* g, float* l) {
    __builtin_amdgcn_global_load_lds((glb_v*)g, (lds_v*)l, 16, 0, 0);
}

// counted vmcnt with memory clobber (pins loads/LDS reads across it)
#define WVS(n) asm volatile("s_waitcnt vmcnt(" #n ")" ::: "memory")
template<int N> __device__ __forceinline__ void waitv() {
    if constexpr (N >= 20)      WVS(20);
    else if constexpr (N >= 16) WVS(16);
    else if constexpr (N >= 14) WVS(14);
    else if constexpr (N >= 12) WVS(12);
    else if constexpr (N >= 10) WVS(10);
    else if constexpr (N >= 8)  WVS(8);
    else                        WVS(6);
}

// VMEM ops issued after STAGE(st)'s 2 gll, up to the wait at iter st.
// Emission order: prologue S0..S3, B0, B1; body st: [S(st+4)] [B(st+2)].
constexpr int after_ops(int KS, int st) {
    int n = 0;
    if (st < 4) {
        n += 2 * (3 - st) + 8;                       // remaining prologue
        for (int k = 0; k < st; k++)
            n += (k + 4 < KS ? 2 : 0) + (k + 2 < KS ? 4 : 0);
    } else {
        n += (st - 2 < KS ? 4 : 0);                  // B(st-2), same body as S(st)
        for (int k = st - 3; k < st; k++)
            n += (k + 4 < KS ? 2 : 0) + (k + 2 < KS ? 4 : 0);
    }
    return n;
}

template<int KS, int ST>
__device__ __forceinline__ void gstep(
    const float* __restrict__ W, const unsigned short* __restrict__ bf,
    float* __restrict__ ldsw, floatx4 (&acc)[4], uintx4 (&bv)[3][4],
    unsigned wbase, unsigned stepInc, unsigned halfInc, unsigned maxoff,
    int q, int l15)
{
    if constexpr (ST < KS) {
        constexpr int AO = after_ops(KS, ST);
        waitv<(AO > 6 ? AO - 6 : 0)>();              // slot ST data is in LDS
        const float* lb = ldsw + (ST & 3) * 512;
        short8 af;
        #pragma unroll
        for (int j = 0; j < 8; j++)
            af[j] = (short)f2bf(lb[(q * 8 + j) * 16 + l15]);
        if constexpr (ST + 4 < KS) {                 // re-stage slot ST&3
            unsigned o0 = wbase + (unsigned)(ST + 4) * stepInc;
            unsigned o1 = o0 + halfInc;
            if (o0 > maxoff) o0 = maxoff;
            if (o1 > maxoff) o1 = maxoff;
            gll16(W + o0, ldsw + ((ST + 4) & 3) * 512);
            gll16(W + o1, ldsw + ((ST + 4) & 3) * 512 + 256);
        }
        if constexpr (ST + 2 < KS) {                 // B prefetch distance 2
            #pragma unroll
            for (int s = 0; s < 4; s++)
                bv[(ST + 2) % 3][s] =
                    *(const uintx4*)(bf + (size_t)((ST + 2) * 4 + s) * 512);
        }
        #pragma unroll
        for (int s = 0; s < 4; s++) {
            short8 b8 = __builtin_bit_cast(short8, bv[ST % 3][s]);
            acc[s] = __builtin_amdgcn_mfma_f32_16x16x32_bf16(af, b8, acc[s], 0, 0, 0);
        }
        gstep<KS, ST + 1>(W, bf, ldsw, acc, bv, wbase, stepInc, halfInc, maxoff, q, l15);
    }
}

// Wave-scoped GEMM unit: 16 cols x KS*32 k-rows. LDS ring of 4 x 512-float
// slots, staged via global_load_lds; OOB handled by address clamping
// (clamped garbage cols -> hpre padding rows; garbage k-rows hit zero-padded
// B fragments). Plain stores into per-chunk partials.
template<int KS>
__device__ __forceinline__ void gemm_wave2(
    const float* __restrict__ W, const unsigned short* __restrict__ Bfc,
    float* __restrict__ pbuf, int ldw, unsigned maxoff, int n0, int k0,
    int lane, float* __restrict__ ldsw)
{
    const int q = lane >> 4, l15 = lane & 15;
    const int r = lane >> 2, c4 = (lane & 3) * 4;
    unsigned wbase = (unsigned)((k0 + r) * ldw + n0 + c4);
    const unsigned stepInc = 32u * (unsigned)ldw;
    const unsigned halfInc = 16u * (unsigned)ldw;

    #pragma unroll
    for (int st = 0; st < 4; st++) {                 // prologue: 4 stages
        unsigned o0 = wbase + (unsigned)st * stepInc;
        unsigned o1 = o0 + halfInc;
        if (o0 > maxoff) o0 = maxoff;
        if (o1 > maxoff) o1 = maxoff;
        gll16(W + o0, ldsw + (st & 3) * 512);
        gll16(W + o1, ldsw + (st & 3) * 512 + 256);
    }
    const unsigned short* bf = Bfc + (size_t)lane * 8;
    uintx4 bv[3][4];
    #pragma unroll
    for (int k = 0; k < 2; k++) {                    // B0, B1
        #pragma unroll
        for (int s = 0; s < 4; s++)
            bv[k][s] = *(const uintx4*)(bf + (size_t)(k * 4 + s) * 512);
    }
    floatx4 acc[4];
    #pragma unroll
    for (int s = 0; s < 4; s++) acc[s] = (floatx4){0.f, 0.f, 0.f, 0.f};

    gstep<KS, 0>(W, bf, ldsw, acc, bv, wbase, stepInc, halfInc, maxoff, q, l15);

    int nrow = n0 + q * 4;
    #pragma unroll
    for (int s = 0; s < 4; s++) {
        #pragma unroll
        for (int rr = 0; rr < 4; rr++)
            pbuf[(size_t)(nrow + rr) * 64 + s * 16 + l15] = acc[s][rr];
    }
}

// Node 1: build gosBf (B-fragment order, zero-padded to 10240)
__global__ __launch_bounds__(256) void prep_k(const float* __restrict__ g,
                                              unsigned short* __restrict__ gosBf) {
    int t    = blockIdx.x * 256 + threadIdx.x;   // [0, 81920)
    int lane = t & 63;
    int sgrp = (t >> 6) & 3;
    int step = t >> 8;                           // [0, 320)
    int q    = lane >> 4;
    int l15  = lane & 15;
    int b    = sgrp * 16 + l15;
    int k0   = step * 32 + q * 8;
    const float* p = g + (size_t)b * IN_SH + k0;
    unsigned int o[4];
    #pragma unroll
    for (int i = 0; i < 4; i++) {
        float lo = (k0 + 2 * i     < IN_SH) ? p[2 * i]     : 0.f;
        float hi = (k0 + 2 * i + 1 < IN_SH) ? p[2 * i + 1] : 0.f;
        o[i] = (unsigned)f2bf(lo) | ((unsigned)f2bf(hi) << 16);
    }
    uintx4 v; v.x = o[0]; v.y = o[1]; v.z = o[2]; v.w = o[3];
    *(uintx4*)(gosBf + (size_t)t * 8) = v;
}

// Node 2: [0,256) hpo colmax; [256,736) GEMM1 partials (ring core)
__global__ __launch_bounds__(256, 4) void gemm1_k(
    const float* __restrict__ W1, const unsigned short* __restrict__ gosBf,
    float* __restrict__ hpre_p, const float* __restrict__ M, float* __restrict__ cm)
{
    __shared__ float lds[4 * 2048];
    int bi = blockIdx.x;
    if (bi < 256) {
        int j  = (bi & 7) * 256 + threadIdx.x;   // 0..2047
        int i0 = (bi >> 3) * 64;
        float m = 0.0f;
        #pragma unroll 16
        for (int i = i0; i < i0 + 64; i++)
            m = fmaxf(m, M[(size_t)i * NBC + j]);
        cm[(bi >> 3) * NBC + j] = m;
    } else {
        int gb  = bi - 256;                      // [0, 480)
        int bx  = gb % 24;
        int by  = gb / 24;
        int wid = threadIdx.x >> 6;
        gemm_wave2<KST1>(W1, gosBf + (size_t)by * (KST1 * 4) * 512,
                         hpre_p + (size_t)by * ACC1, HID,
                         (unsigned)(IN_SH * HID - 4),
                         bx * 64 + wid * 16, by * (KST1 * 32),
                         threadIdx.x & 63, lds + wid * 2048);
    }
}

// Node 4: GEMM2 partials (ring core)
__global__ __launch_bounds__(256, 4) void gemm2_k(
    const float* __restrict__ W2, const unsigned short* __restrict__ Xf,
    float* __restrict__ logits_p)
{
    __shared__ float lds[4 * 2048];
    int wid = threadIdx.x >> 6;
    gemm_wave2<KST2>(W2, Xf + (size_t)blockIdx.y * (KST2 * 4) * 512,
                     logits_p + (size_t)blockIdx.y * ACC2, NBC,
                     (unsigned)(K2 * NBC - 4),
                     blockIdx.x * 64 + wid * 16, blockIdx.y * (KST2 * 32),
                     threadIdx.x & 63, lds + wid * 2048);
}

// Node 3: [0,208) reduce 20 partials + bias + GELU + concat -> Xf, fully
// coalesced (thread = (n-pair, b); 40 independent 256B-coalesced streams);
// [208,216) reduce cm -> cmr.
__global__ __launch_bounds__(256) void combine1(
    const float* __restrict__ hpre_p, const float* __restrict__ b1,
    const float* __restrict__ expx, unsigned short* __restrict__ Xf,
    const float* __restrict__ cm, float* __restrict__ cmr)
{
    int bi = blockIdx.x;
    if (bi < 208) {
        int idx = bi * 256 + threadIdx.x;        // [0, 53248)
        int b   = idx & 63;
        int n0  = (idx >> 6) * 2;                // even n in [0, 1664)
        float v[2];
        #pragma unroll
        for (int e = 0; e < 2; e++) {
            int n = n0 + e;
            float x = 0.f;
            if (n < HID) {
                const float* p = hpre_p + (size_t)n * 64 + b;
                float a0 = 0.f, a1 = 0.f, a2 = 0.f, a3 = 0.f;
                #pragma unroll
                for (int ks = 0; ks < KS1; ks += 4) {
                    a0 += p[(size_t)ks * ACC1];
                    a1 += p[(size_t)(ks + 1) * ACC1];
                    a2 += p[(size_t)(ks + 2) * ACC1];
                    a3 += p[(size_t)(ks + 3) * ACC1];
                }
                float s = b1[n] + ((a0 + a1) + (a2 + a3));
                x = 0.5f * s * (1.0f + erff(s * 0.70710678118654752f));
            } else if (n < HID + EXP_SH) {
                x = expx[b * EXP_SH + (n - HID)];
            }
            v[e] = x;
        }
        unsigned o = (unsigned)f2bf(v[0]) | ((unsigned)f2bf(v[1]) << 16);
        int step = n0 >> 5, w = n0 & 31, q = w >> 3, j = w & 7;
        int sgrp = b >> 4, l15 = b & 15;
        size_t tq = (size_t)(step * 4 + sgrp) * 64 + q * 16 + l15;
        *(unsigned*)(Xf + tq * 8 + j) = o;
    } else {
        int j = (bi - 208) * 256 + threadIdx.x;  // 0..2047
        float m = 0.f;
        #pragma unroll
        for (int c = 0; c < CMCH; c++) m = fmaxf(m, cm[c * NBC + j]);
        cmr[j] = m;
    }
}

// Node 5: reduce 13 partials + bias + sigmoid + *cmr -> out (LDS transpose
// for 128B-contiguous out rows)
__global__ __launch_bounds__(256) void final_k(
    const float* __restrict__ logits_p, const float* __restrict__ b2,
    const float* __restrict__ cmr, float* __restrict__ out)
{
    __shared__ float lds[32 * 65];
    int j0  = blockIdx.x * 32;
    int tid = threadIdx.x;
    #pragma unroll
    for (int e = 0; e < 8; e++) {
        int lin = e * 256 + tid;            // j-major, b-minor
        int jj  = lin >> 6;
        int b   = lin & 63;
        int j   = j0 + jj;
        float s = b2[j];
        const float* p = logits_p + (size_t)j * 64 + b;
        #pragma unroll
        for (int ks = 0; ks < KS2; ks++)
            s += p[(size_t)ks * ACC2];
        float sig = 1.0f / (1.0f + expf(-s));
        lds[jj * 65 + b] = sig * cmr[j];
    }
    __syncthreads();
    #pragma unroll
    for (int e = 0; e < 8; e++) {
        int lin = e * 256 + tid;            // b-major, j-minor
        int b   = lin >> 5;
        int jj  = lin & 31;
        out[(size_t)b * NBC + j0 + jj] = lds[jj * 65 + b];
    }
}

extern "C" void kernel_launch(void* const* d_in, const int* in_sizes, int n_in,
                              void* d_out, int out_size, void* d_ws, size_t ws_size,
                              hipStream_t stream) {
    const float* gos  = (const float*)d_in[0];
    const float* expx = (const float*)d_in[1];
    const float* W1   = (const float*)d_in[2];
    const float* b1   = (const float*)d_in[3];
    const float* W2   = (const float*)d_in[4];
    const float* b2   = (const float*)d_in[5];
    const float* hpo  = (const float*)d_in[6];
    float* out = (float*)d_out;

    // workspace layout (16B-aligned offsets)
    char* ws = (char*)d_ws;
    unsigned short* gosBf = (unsigned short*)ws;                   // 1,310,720
    unsigned short* Xf    = (unsigned short*)(ws + 1310720);       //   212,992
    float* cm       = (float*)(ws + 1523712);                      //   262,144
    float* cmr      = (float*)(ws + 1785856);                      //     8,192
    float* hpre_p   = (float*)(ws + 1794048);                      // 20*393,216 = 7,864,320
    float* logits_p = (float*)(ws + 9658368);                      // 13*524,288 = 6,815,744
    // total ~16.5 MB

    // 1) build gosBf
    prep_k<<<320, 256, 0, stream>>>(gos, gosBf);

    // 2) hpo colmax (256 blocks) + GEMM1 partials (480 blocks, ring core)
    gemm1_k<<<256 + 24 * KS1, 256, 0, stream>>>(W1, gosBf, hpre_p, hpo, cm);

    // 3) reduce partials + bias + gelu + concat -> Xf | reduce cm -> cmr
    combine1<<<216, 256, 0, stream>>>(hpre_p, b1, expx, Xf, cm, cmr);

    // 4) GEMM2 partials (32x13 blocks, ring core)
    gemm2_k<<<dim3(32, KS2), 256, 0, stream>>>(W2, Xf, logits_p);

    // 5) reduce partials + bias + sigmoid + *cmr -> out
    final_k<<<64, 256, 0, stream>>>(logits_p, b2, cmr, out);
}